// Round 11
// baseline (306.054 us; speedup 1.0000x reference)
//
#include <hip/hip_runtime.h>
#include <hip/hip_bf16.h>

// Problem constants
#define B_ 16
#define N_ 512
#define H_ 8
#define D_ 128
#define HD_ 1024
#define SCALE_ 0.08838834764831845f  // 1/sqrt(128)

typedef __attribute__((ext_vector_type(8))) short bf16x8;     // 8 bf16 = 4 VGPR
typedef __attribute__((ext_vector_type(4))) float f32x4;      // MFMA 16x16 C/D
typedef __attribute__((ext_vector_type(4))) _Float16 f16x4;   // 16x16x16 A/B

__device__ __forceinline__ unsigned short f2bf(float f) {
    union { __hip_bfloat16 h; unsigned short u; } cv;
    cv.h = __float2bfloat16(f);
    return cv.u;
}
__device__ __forceinline__ float bf2f(unsigned short u) {
    union { unsigned int i; float f; } cv;
    cv.i = ((unsigned int)u) << 16;
    return cv.f;
}
__device__ __forceinline__ unsigned short f2h(float f) {
    union { _Float16 h; unsigned short u; } cv;
    cv.h = (_Float16)f;
    return cv.u;
}

// ---------------------------------------------------------------------------
// Kernel 0: weight prep. wTh: [3][1024][128] bf16 of Wq,Wk,Wv transposed;
// woT: [128][1024] bf16 of Wo transposed.
// ---------------------------------------------------------------------------
__global__ __launch_bounds__(256) void prep_kernel(
    const float* __restrict__ Wq, const float* __restrict__ Wk,
    const float* __restrict__ Wv, const float* __restrict__ Wo,
    unsigned short* __restrict__ wTh, unsigned short* __restrict__ woT)
{
    __shared__ float T[32][33];
    const int tile = blockIdx.x;
    const int t = threadIdx.x;
    if (tile < 384) {
        const int w = tile / 128;
        const int rem = tile % 128;
        const int kt = rem & 3;
        const int ct = rem >> 2;
        const float* W = (w == 0) ? Wq : (w == 1) ? Wk : Wv;
        const int k0 = kt * 32, c0 = ct * 32;
        #pragma unroll
        for (int u = 0; u < 4; u++) {
            int lin = t + 256 * u; int r = lin >> 5, c = lin & 31;
            T[r][c] = W[(size_t)(k0 + r) * 1024 + c0 + c];
        }
        __syncthreads();
        unsigned short* oh = wTh + (size_t)w * 131072;
        #pragma unroll
        for (int u = 0; u < 4; u++) {
            int lin = t + 256 * u; int c = lin >> 5, r = lin & 31;
            oh[(size_t)(c0 + c) * 128 + k0 + r] = f2bf(T[r][c]);
        }
    } else {
        const int rem = tile - 384;
        const int nt = rem & 3;
        const int kt = rem >> 2;
        const int k0 = kt * 32, n0 = nt * 32;
        #pragma unroll
        for (int u = 0; u < 4; u++) {
            int lin = t + 256 * u; int r = lin >> 5, c = lin & 31;
            T[r][c] = Wo[(size_t)(k0 + r) * 128 + n0 + c];
        }
        __syncthreads();
        #pragma unroll
        for (int u = 0; u < 4; u++) {
            int lin = t + 256 * u; int c = lin >> 5, r = lin & 31;
            woT[(size_t)(n0 + c) * 1024 + k0 + r] = f2bf(T[r][c]);
        }
    }
}

// ---------------------------------------------------------------------------
// Kernel 1: QKV projection, 128 rows x 128 cols per block (grid 1536).
// x loaded fp32 straight from global and hi/lo-split IN REGISTERS; only W
// staged in LDS -> one barrier. q,k bf16 (B,H,N,D) *mask (q also *scale);
// v f16 transposed (B,H,D,N) *mask.
// ---------------------------------------------------------------------------
__global__ __launch_bounds__(256, 2) void qkv_kernel(
    const float* __restrict__ x, const float* __restrict__ mask,
    const unsigned short* __restrict__ wTh,
    const float* __restrict__ bq, const float* __restrict__ bk,
    const float* __restrict__ bv,
    unsigned short* __restrict__ q, unsigned short* __restrict__ k,
    unsigned short* __restrict__ vT)
{
    const int cb = blockIdx.x % 24;
    const int by = blockIdx.x / 24;
    const int row0 = by * 128, c0 = cb * 128;
    const int which = c0 >> 10, w0 = c0 & 1023;
    const float* bi = (which == 0) ? bq : (which == 1) ? bk : bv;

    __shared__ alignas(16) unsigned short Wh[128][136];  // 34.8 KB
    __shared__ float biS[128];
    __shared__ float mskS[128];

    const int t = threadIdx.x;
    if (t < 128) { biS[t] = bi[w0 + t]; mskS[t] = mask[row0 + t]; }

    const unsigned short* whp = wTh + (size_t)which * 131072 + (size_t)w0 * 128;
    #pragma unroll
    for (int u = 0; u < 8; u++) {
        int lin = t + 256 * u; int c = lin >> 4, k8 = (lin & 15) * 8;
        *(bf16x8*)&Wh[c][k8] = *(const bf16x8*)&whp[(size_t)c * 128 + k8];
    }

    const int wave = t >> 6, lane = t & 63, m16 = lane & 15, g4 = lane >> 4;
    const int rw = row0 + wave * 32;

    bf16x8 ah[2][4], al[2][4];
    #pragma unroll
    for (int mt = 0; mt < 2; mt++)
        #pragma unroll
        for (int kc = 0; kc < 4; kc++) {
            const float* xp = &x[(size_t)(rw + mt * 16 + m16) * 128 + kc * 32 + g4 * 8];
            float4 v0 = *(const float4*)xp;
            float4 v1 = *(const float4*)(xp + 4);
            float vv[8] = {v0.x, v0.y, v0.z, v0.w, v1.x, v1.y, v1.z, v1.w};
            union { bf16x8 v; unsigned short s[8]; } Hh, Ll;
            #pragma unroll
            for (int e = 0; e < 8; e++) {
                Hh.s[e] = f2bf(vv[e]);
                Ll.s[e] = f2bf(vv[e] - bf2f(Hh.s[e]));
            }
            ah[mt][kc] = Hh.v;
            al[mt][kc] = Ll.v;
        }
    __syncthreads();

    const f32x4 zero = {0.f, 0.f, 0.f, 0.f};
    f32x4 acc[2][8];
    #pragma unroll
    for (int mt = 0; mt < 2; mt++)
        #pragma unroll
        for (int nt = 0; nt < 8; nt++) acc[mt][nt] = zero;

    #pragma unroll
    for (int nt = 0; nt < 8; nt++) {
        #pragma unroll
        for (int kc = 0; kc < 4; kc++) {
            bf16x8 bh = *(const bf16x8*)&Wh[nt * 16 + m16][kc * 32 + g4 * 8];
            #pragma unroll
            for (int mt = 0; mt < 2; mt++) {
                acc[mt][nt] = __builtin_amdgcn_mfma_f32_16x16x32_bf16(ah[mt][kc], bh, acc[mt][nt], 0, 0, 0);
                acc[mt][nt] = __builtin_amdgcn_mfma_f32_16x16x32_bf16(al[mt][kc], bh, acc[mt][nt], 0, 0, 0);
            }
        }
    }
    __syncthreads();  // done reading Wh; reuse as transpose staging

    const int b = row0 >> 9, h = w0 >> 7;
    const int iseq0 = row0 & 511;
    unsigned short* Tr = &Wh[0][0];

    if (which == 2) {
        #pragma unroll
        for (int mt = 0; mt < 2; mt++)
            #pragma unroll
            for (int nt = 0; nt < 8; nt++)
                #pragma unroll
                for (int r = 0; r < 4; r++) {
                    int rowl = wave * 32 + mt * 16 + g4 * 4 + r;
                    int col = nt * 16 + m16;
                    Tr[col * 136 + rowl] = f2h((acc[mt][nt][r] + biS[col]) * mskS[rowl]);
                }
        __syncthreads();
        unsigned short* vbase = vT + (size_t)(b * 8 + h) * 128 * 512 + iseq0;
        #pragma unroll
        for (int u = 0; u < 8; u++) {
            int lin = t + 256 * u; int dl = lin >> 4, i8 = (lin & 15) * 8;
            *(bf16x8*)&vbase[(size_t)dl * 512 + i8] = *(const bf16x8*)&Tr[dl * 136 + i8];
        }
    } else {
        const float sc = (which == 0) ? SCALE_ : 1.0f;
        #pragma unroll
        for (int mt = 0; mt < 2; mt++)
            #pragma unroll
            for (int nt = 0; nt < 8; nt++)
                #pragma unroll
                for (int r = 0; r < 4; r++) {
                    int rowl = wave * 32 + mt * 16 + g4 * 4 + r;
                    int col = nt * 16 + m16;
                    Tr[rowl * 136 + col] = f2bf((acc[mt][nt][r] + biS[col]) * (mskS[rowl] * sc));
                }
        __syncthreads();
        unsigned short* dst = ((which == 0) ? q : k) +
                              ((size_t)(b * 8 + h) * 512 + iseq0) * 128;
        #pragma unroll
        for (int u = 0; u < 8; u++) {
            int lin = t + 256 * u; int rl = lin >> 4, c8 = (lin & 15) * 8;
            *(bf16x8*)&dst[(size_t)rl * 128 + c8] = *(const bf16x8*)&Tr[rl * 136 + c8];
        }
    }
}

// ---------------------------------------------------------------------------
// Kernel 2: flash attention, S^T trick, BARRIER-FREE. Block = (b,h, 64 q).
// No LDS K/V staging: each wave loads K (A-frag b128), V (f16x4 b64), dist
// (float4) and mask directly from global -- 4x redundant within a block but
// L2-resident on one XCD (swizzle). Zero __syncthreads: waves co-schedule
// MFMA/VALU/loads freely (m114 overlap). LDS = epilogue staging only
// (same-wave round-trip, wave-order safe). Column mask folded inline into
// the MFMA C-initializer; row mask handled by oproj's final multiply.
// ---------------------------------------------------------------------------
__global__ __launch_bounds__(256) void attn_kernel(
    const unsigned short* __restrict__ q, const unsigned short* __restrict__ k,
    const unsigned short* __restrict__ vT, const float* __restrict__ dist,
    const float* __restrict__ mask, unsigned short* __restrict__ y)
{
    const int xid = blockIdx.x;                       // 1024 blocks
    const int bh = (xid & 7) | ((xid >> 6) << 3);     // XCD = xid&7 = h
    const int itile = (xid >> 3) & 7;
    const int b = bh >> 3, h = bh & 7;
    const int i0 = itile * 64;

    const unsigned short* qb = q + (size_t)bh * 512 * 128;
    const unsigned short* kb = k + (size_t)bh * 512 * 128;
    const unsigned short* vb = vT + (size_t)bh * 128 * 512;  // f16 (d, j)

    __shared__ alignas(16) unsigned short Yst[64][136];  // epilogue only

    const int t = threadIdx.x;
    const int wave = t >> 6, lane = t & 63;
    const int m16 = lane & 15, g4 = lane >> 4;
    const int iw = i0 + wave * 16;

    // Q fragments: MFMA B-operand (n=i=m16, k=d)
    bf16x8 aq[4];
    #pragma unroll
    for (int c = 0; c < 4; c++)
        aq[c] = *(const bf16x8*)(qb + (size_t)(iw + m16) * 128 + c * 32 + g4 * 8);

    const float* dbase = dist + ((size_t)b * 512 + iw) * 512;
    const float* mbase = mask + b * 512;
    const f32x4 zero = {0.f, 0.f, 0.f, 0.f};

    float rm = -3.0e38f, rl = 0.f;   // per-lane softmax state (row i = iw+m16)
    f32x4 Ot[8] = {zero, zero, zero, zero, zero, zero, zero, zero};

    for (int c = 0; c < 8; c++) {
        const int j0 = c * 64;

        // S^T = K*Q^T, C = dist + column-mask (inline), all from global.
        // lane gets S[i=m16][j = j0 + jt*16 + g4*4 + r]
        f32x4 s[4];
        #pragma unroll
        for (int jt = 0; jt < 4; jt++) {
            const int jc = j0 + jt * 16 + g4 * 4;
            float4 dv = *(const float4*)&dbase[(size_t)m16 * 512 + jc];
            float4 mj = *(const float4*)&mbase[jc];
            f32x4 a;
            a[0] = (mj.x == 0.0f) ? -1e9f : dv.x;
            a[1] = (mj.y == 0.0f) ? -1e9f : dv.y;
            a[2] = (mj.z == 0.0f) ? -1e9f : dv.z;
            a[3] = (mj.w == 0.0f) ? -1e9f : dv.w;
            #pragma unroll
            for (int cc = 0; cc < 4; cc++) {
                bf16x8 kf = *(const bf16x8*)(kb + (size_t)(j0 + jt * 16 + m16) * 128 + cc * 32 + g4 * 8);
                a = __builtin_amdgcn_mfma_f32_16x16x32_bf16(kf, aq[cc], a, 0, 0, 0);
            }
            s[jt] = a;
        }

        // chunk max: per-lane over 16 + 2 shuffles
        float cm = -3.0e38f;
        #pragma unroll
        for (int jt = 0; jt < 4; jt++)
            #pragma unroll
            for (int r = 0; r < 4; r++) cm = fmaxf(cm, s[jt][r]);
        cm = fmaxf(cm, __shfl_xor(cm, 16));
        cm = fmaxf(cm, __shfl_xor(cm, 32));

        float nm = fmaxf(rm, cm);
        float alpha = __expf(rm - nm);
        rm = nm;
        rl *= alpha;

        // P in f16 regs = PV A-fragments (k = g4*4 + r)
        f16x4 pa[4];
        float ps = 0.f;
        #pragma unroll
        for (int jt = 0; jt < 4; jt++) {
            #pragma unroll
            for (int r = 0; r < 4; r++) {
                float p = __expf(s[jt][r] - rm);
                ps += p;
                pa[jt][r] = (_Float16)p;
            }
        }
        ps += __shfl_xor(ps, 16);
        ps += __shfl_xor(ps, 32);
        rl += ps;

        // rescale Ot (rows g4*4+r) by alpha of those rows
        float a4[4];
        #pragma unroll
        for (int r = 0; r < 4; r++) a4[r] = __shfl(alpha, g4 * 4 + r);
        #pragma unroll
        for (int dt = 0; dt < 8; dt++)
            #pragma unroll
            for (int r = 0; r < 4; r++) Ot[dt][r] *= a4[r];

        // PV: 8 d-tiles x 4 jt, B-frag = f16x4 straight from global vT
        #pragma unroll
        for (int dt = 0; dt < 8; dt++) {
            #pragma unroll
            for (int jt = 0; jt < 4; jt++) {
                f16x4 vf = *(const f16x4*)(vb + (size_t)(dt * 16 + m16) * 512 + j0 + jt * 16 + g4 * 4);
                Ot[dt] = __builtin_amdgcn_mfma_f32_16x16x16f16(pa[jt], vf, Ot[dt], 0, 0, 0);
            }
        }
    }

    // epilogue: normalize, stage wave-private rows in LDS (same-wave
    // round-trip: wave-order + lgkmcnt, no barrier), coalesced bf16x8 stores
    float rs = (rl > 0.f) ? 1.0f / rl : 0.f;
    float rs4[4];
    #pragma unroll
    for (int r = 0; r < 4; r++) rs4[r] = __shfl(rs, g4 * 4 + r);
    #pragma unroll
    for (int dt = 0; dt < 8; dt++)
        #pragma unroll
        for (int r = 0; r < 4; r++)
            Yst[wave * 16 + g4 * 4 + r][dt * 16 + m16] = f2bf(Ot[dt][r] * rs4[r]);
    #pragma unroll
    for (int u = 0; u < 4; u++) {
        int lin = lane + 64 * u;
        int row = lin >> 4, seg = lin & 15;
        *(bf16x8*)&y[((size_t)(b * 512) + iw + row) * 1024 + h * 128 + seg * 8] =
            *(const bf16x8*)&Yst[wave * 16 + row][seg * 8];
    }
}

// ---------------------------------------------------------------------------
// Kernel 3: output projection via bf16 MFMA with depth-1 register prefetch.
// ---------------------------------------------------------------------------
__global__ __launch_bounds__(256) void oproj_kernel(
    const unsigned short* __restrict__ Y, const unsigned short* __restrict__ woT,
    const float* __restrict__ bo, const float* __restrict__ mask,
    float* __restrict__ out)
{
    const int row0 = blockIdx.x * 32;
    __shared__ alignas(16) unsigned short Ys[32][136];
    __shared__ alignas(16) unsigned short Ws[128][136];
    __shared__ float boS[128];
    __shared__ float mskS[32];

    const int t = threadIdx.x;
    if (t < 128) boS[t] = bo[t];
    if (t < 32) mskS[t] = mask[row0 + t];

    const int wave = t >> 6, lane = t & 63;
    const int m16 = lane & 15, g4 = lane >> 4;
    const int mrow = (wave & 1) * 16, n0 = (wave >> 1) * 64;

    const int yr = t >> 4, yk = (t & 15) * 8;
    const int wn = t >> 4, wk = (t & 15) * 8;

    const f32x4 zero = {0.f, 0.f, 0.f, 0.f};
    f32x4 acc[4] = {zero, zero, zero, zero};

    bf16x8 yp[2], wp[8];
    #pragma unroll
    for (int u = 0; u < 2; u++)
        yp[u] = *(const bf16x8*)&Y[(size_t)(row0 + yr + u * 16) * 1024 + yk];
    #pragma unroll
    for (int u = 0; u < 8; u++)
        wp[u] = *(const bf16x8*)&woT[(size_t)(wn + u * 16) * 1024 + wk];

    for (int c = 0; c < 8; c++) {
        __syncthreads();
        #pragma unroll
        for (int u = 0; u < 2; u++) *(bf16x8*)&Ys[yr + u * 16][yk] = yp[u];
        #pragma unroll
        for (int u = 0; u < 8; u++) *(bf16x8*)&Ws[wn + u * 16][wk] = wp[u];
        __syncthreads();
        if (c < 7) {
            const int kc0 = (c + 1) * 128;
            #pragma unroll
            for (int u = 0; u < 2; u++)
                yp[u] = *(const bf16x8*)&Y[(size_t)(row0 + yr + u * 16) * 1024 + kc0 + yk];
            #pragma unroll
            for (int u = 0; u < 8; u++)
                wp[u] = *(const bf16x8*)&woT[(size_t)(wn + u * 16) * 1024 + kc0 + wk];
        }
        #pragma unroll
        for (int kc = 0; kc < 4; kc++) {
            bf16x8 a = *(const bf16x8*)&Ys[mrow + m16][kc * 32 + g4 * 8];
            #pragma unroll
            for (int nt = 0; nt < 4; nt++) {
                bf16x8 bb = *(const bf16x8*)&Ws[n0 + nt * 16 + m16][kc * 32 + g4 * 8];
                acc[nt] = __builtin_amdgcn_mfma_f32_16x16x32_bf16(a, bb, acc[nt], 0, 0, 0);
            }
        }
    }
    __syncthreads();

    float* Ot = (float*)&Ws[0][0];  // stride 132
    #pragma unroll
    for (int nt = 0; nt < 4; nt++)
        #pragma unroll
        for (int r = 0; r < 4; r++) {
            int rowl = mrow + g4 * 4 + r;
            int col = n0 + nt * 16 + m16;
            Ot[rowl * 132 + col] = (acc[nt][r] + boS[col]) * mskS[rowl];
        }
    __syncthreads();
    #pragma unroll
    for (int u = 0; u < 4; u++) {
        int lin = t + 256 * u; int r = lin >> 5, c4 = lin & 31;
        *(float4*)&out[(size_t)(row0 + r) * 128 + c4 * 4] =
            *(const float4*)&Ot[r * 132 + c4 * 4];
    }
}

extern "C" void kernel_launch(void* const* d_in, const int* in_sizes, int n_in,
                              void* d_out, int out_size, void* d_ws, size_t ws_size,
                              hipStream_t stream) {
    const float* x    = (const float*)d_in[0];
    const float* dist = (const float*)d_in[1];
    const float* mask = (const float*)d_in[2];
    const float* Wq   = (const float*)d_in[3];
    const float* bq   = (const float*)d_in[4];
    const float* Wk   = (const float*)d_in[5];
    const float* bk   = (const float*)d_in[6];
    const float* Wv   = (const float*)d_in[7];
    const float* bv   = (const float*)d_in[8];
    const float* Wo   = (const float*)d_in[9];
    const float* bo   = (const float*)d_in[10];
    float* out = (float*)d_out;

    const size_t per = (size_t)B_ * H_ * N_ * D_;  // 8,388,608 elements
    unsigned short* qb  = (unsigned short*)d_ws;   // bf16 (B,H,N,D)
    unsigned short* kb  = qb + per;                // bf16 (B,H,N,D)
    unsigned short* vb  = kb + per;                // f16  (B,H,D,N)
    unsigned short* yb  = vb + per;                // bf16 (B,N,H*D)
    unsigned short* wTh = yb + per;                // [3][1024][128]
    unsigned short* woT = wTh + 3 * 131072;        // [128][1024]

    prep_kernel<<<512, 256, 0, stream>>>(Wq, Wk, Wv, Wo, wTh, woT);
    qkv_kernel<<<1536, 256, 0, stream>>>(x, mask, wTh, bq, bk, bv, qb, kb, vb);
    attn_kernel<<<1024, 256, 0, stream>>>(qb, kb, vb, dist, mask, yb);
    oproj_kernel<<<256, 256, 0, stream>>>(yb, woT, bo, mask, out);
}

// Round 12
// 159.508 us; speedup vs baseline: 1.9187x; 1.9187x over previous
//
#include <hip/hip_runtime.h>
#include <hip/hip_bf16.h>

// Problem constants
#define B_ 16
#define N_ 512
#define H_ 8
#define D_ 128
#define HD_ 1024
#define SCALE_ 0.08838834764831845f  // 1/sqrt(128)

typedef __attribute__((ext_vector_type(8))) short bf16x8;     // 8 bf16 = 4 VGPR
typedef __attribute__((ext_vector_type(4))) float f32x4;      // MFMA 16x16 C/D
typedef __attribute__((ext_vector_type(4))) _Float16 f16x4;   // 16x16x16 A/B

__device__ __forceinline__ unsigned short f2bf(float f) {
    union { __hip_bfloat16 h; unsigned short u; } cv;
    cv.h = __float2bfloat16(f);
    return cv.u;
}
__device__ __forceinline__ unsigned short f2h(float f) {
    union { _Float16 h; unsigned short u; } cv;
    cv.h = (_Float16)f;
    return cv.u;
}

// ---------------------------------------------------------------------------
// Kernel 0: weight prep. wTh: [3][1024][128] bf16 of Wq,Wk,Wv transposed;
// woT: [128][1024] bf16 of Wo transposed.
// ---------------------------------------------------------------------------
__global__ __launch_bounds__(256) void prep_kernel(
    const float* __restrict__ Wq, const float* __restrict__ Wk,
    const float* __restrict__ Wv, const float* __restrict__ Wo,
    unsigned short* __restrict__ wTh, unsigned short* __restrict__ woT)
{
    __shared__ float T[32][33];
    const int tile = blockIdx.x;
    const int t = threadIdx.x;
    if (tile < 384) {
        const int w = tile / 128;
        const int rem = tile % 128;
        const int kt = rem & 3;
        const int ct = rem >> 2;
        const float* W = (w == 0) ? Wq : (w == 1) ? Wk : Wv;
        const int k0 = kt * 32, c0 = ct * 32;
        #pragma unroll
        for (int u = 0; u < 4; u++) {
            int lin = t + 256 * u; int r = lin >> 5, c = lin & 31;
            T[r][c] = W[(size_t)(k0 + r) * 1024 + c0 + c];
        }
        __syncthreads();
        unsigned short* oh = wTh + (size_t)w * 131072;
        #pragma unroll
        for (int u = 0; u < 4; u++) {
            int lin = t + 256 * u; int c = lin >> 5, r = lin & 31;
            oh[(size_t)(c0 + c) * 128 + k0 + r] = f2bf(T[r][c]);
        }
    } else {
        const int rem = tile - 384;
        const int nt = rem & 3;
        const int kt = rem >> 2;
        const int k0 = kt * 32, n0 = nt * 32;
        #pragma unroll
        for (int u = 0; u < 4; u++) {
            int lin = t + 256 * u; int r = lin >> 5, c = lin & 31;
            T[r][c] = Wo[(size_t)(k0 + r) * 128 + n0 + c];
        }
        __syncthreads();
        #pragma unroll
        for (int u = 0; u < 4; u++) {
            int lin = t + 256 * u; int c = lin >> 5, r = lin & 31;
            woT[(size_t)(n0 + c) * 1024 + k0 + r] = f2bf(T[r][c]);
        }
    }
}

// ---------------------------------------------------------------------------
// Kernel 1: QKV projection, 128 rows x 128 cols per block (grid 1536).
// Single bf16 pass (xl low-order term dropped: outputs are stored bf16/f16,
// so store-rounding dominates anyway). x loaded fp32 straight from global,
// converted in registers; only W staged in LDS -> one barrier.
// q,k bf16 (B,H,N,D) *mask (q also *scale); v f16 transposed (B,H,D,N).
// ---------------------------------------------------------------------------
__global__ __launch_bounds__(256, 2) void qkv_kernel(
    const float* __restrict__ x, const float* __restrict__ mask,
    const unsigned short* __restrict__ wTh,
    const float* __restrict__ bq, const float* __restrict__ bk,
    const float* __restrict__ bv,
    unsigned short* __restrict__ q, unsigned short* __restrict__ k,
    unsigned short* __restrict__ vT)
{
    const int cb = blockIdx.x % 24;
    const int by = blockIdx.x / 24;
    const int row0 = by * 128, c0 = cb * 128;
    const int which = c0 >> 10, w0 = c0 & 1023;
    const float* bi = (which == 0) ? bq : (which == 1) ? bk : bv;

    __shared__ alignas(16) unsigned short Wh[128][136];  // 34.8 KB
    __shared__ float biS[128];
    __shared__ float mskS[128];

    const int t = threadIdx.x;
    if (t < 128) { biS[t] = bi[w0 + t]; mskS[t] = mask[row0 + t]; }

    const unsigned short* whp = wTh + (size_t)which * 131072 + (size_t)w0 * 128;
    #pragma unroll
    for (int u = 0; u < 8; u++) {
        int lin = t + 256 * u; int c = lin >> 4, k8 = (lin & 15) * 8;
        *(bf16x8*)&Wh[c][k8] = *(const bf16x8*)&whp[(size_t)c * 128 + k8];
    }

    const int wave = t >> 6, lane = t & 63, m16 = lane & 15, g4 = lane >> 4;
    const int rw = row0 + wave * 32;

    bf16x8 ah[2][4];
    #pragma unroll
    for (int mt = 0; mt < 2; mt++)
        #pragma unroll
        for (int kc = 0; kc < 4; kc++) {
            const float* xp = &x[(size_t)(rw + mt * 16 + m16) * 128 + kc * 32 + g4 * 8];
            float4 v0 = *(const float4*)xp;
            float4 v1 = *(const float4*)(xp + 4);
            float vv[8] = {v0.x, v0.y, v0.z, v0.w, v1.x, v1.y, v1.z, v1.w};
            union { bf16x8 v; unsigned short s[8]; } Hh;
            #pragma unroll
            for (int e = 0; e < 8; e++) Hh.s[e] = f2bf(vv[e]);
            ah[mt][kc] = Hh.v;
        }
    __syncthreads();

    const f32x4 zero = {0.f, 0.f, 0.f, 0.f};
    f32x4 acc[2][8];
    #pragma unroll
    for (int mt = 0; mt < 2; mt++)
        #pragma unroll
        for (int nt = 0; nt < 8; nt++) acc[mt][nt] = zero;

    #pragma unroll
    for (int nt = 0; nt < 8; nt++) {
        #pragma unroll
        for (int kc = 0; kc < 4; kc++) {
            bf16x8 bh = *(const bf16x8*)&Wh[nt * 16 + m16][kc * 32 + g4 * 8];
            #pragma unroll
            for (int mt = 0; mt < 2; mt++)
                acc[mt][nt] = __builtin_amdgcn_mfma_f32_16x16x32_bf16(ah[mt][kc], bh, acc[mt][nt], 0, 0, 0);
        }
    }
    __syncthreads();  // done reading Wh; reuse as transpose staging

    const int b = row0 >> 9, h = w0 >> 7;
    const int iseq0 = row0 & 511;
    unsigned short* Tr = &Wh[0][0];

    if (which == 2) {
        #pragma unroll
        for (int mt = 0; mt < 2; mt++)
            #pragma unroll
            for (int nt = 0; nt < 8; nt++)
                #pragma unroll
                for (int r = 0; r < 4; r++) {
                    int rowl = wave * 32 + mt * 16 + g4 * 4 + r;
                    int col = nt * 16 + m16;
                    Tr[col * 136 + rowl] = f2h((acc[mt][nt][r] + biS[col]) * mskS[rowl]);
                }
        __syncthreads();
        unsigned short* vbase = vT + (size_t)(b * 8 + h) * 128 * 512 + iseq0;
        #pragma unroll
        for (int u = 0; u < 8; u++) {
            int lin = t + 256 * u; int dl = lin >> 4, i8 = (lin & 15) * 8;
            *(bf16x8*)&vbase[(size_t)dl * 512 + i8] = *(const bf16x8*)&Tr[dl * 136 + i8];
        }
    } else {
        const float sc = (which == 0) ? SCALE_ : 1.0f;
        #pragma unroll
        for (int mt = 0; mt < 2; mt++)
            #pragma unroll
            for (int nt = 0; nt < 8; nt++)
                #pragma unroll
                for (int r = 0; r < 4; r++) {
                    int rowl = wave * 32 + mt * 16 + g4 * 4 + r;
                    int col = nt * 16 + m16;
                    Tr[rowl * 136 + col] = f2bf((acc[mt][nt][r] + biS[col]) * (mskS[rowl] * sc));
                }
        __syncthreads();
        unsigned short* dst = ((which == 0) ? q : k) +
                              ((size_t)(b * 8 + h) * 512 + iseq0) * 128;
        #pragma unroll
        for (int u = 0; u < 8; u++) {
            int lin = t + 256 * u; int rl = lin >> 4, c8 = (lin & 15) * 8;
            *(bf16x8*)&dst[(size_t)rl * 128 + c8] = *(const bf16x8*)&Tr[rl * 136 + c8];
        }
    }
}

// ---------------------------------------------------------------------------
// Kernel 2: flash attention, S^T trick (R10 structure, measured 52 us).
// Block = (b,h, 64 q-rows). K/V staged in LDS (load-bearing: converts L2
// latency into 4-wave-amortized LDS reads — R11's barrier-free global-feed
// variant was 3.8x slower). Column mask in cmS LDS; C-init = dist + cm.
// Depth-1 register prefetch of K/V/dist. Swizzle pins a head's 8 i-tiles
// to one XCD.
// ---------------------------------------------------------------------------
__global__ __launch_bounds__(256, 2) void attn_kernel(
    const unsigned short* __restrict__ q, const unsigned short* __restrict__ k,
    const unsigned short* __restrict__ vT, const float* __restrict__ dist,
    const float* __restrict__ mask, unsigned short* __restrict__ y)
{
    const int xid = blockIdx.x;                       // 1024 blocks
    const int bh = (xid & 7) | ((xid >> 6) << 3);     // XCD = xid&7 = h
    const int itile = (xid >> 3) & 7;
    const int b = bh >> 3, h = bh & 7;
    const int i0 = itile * 64;

    const unsigned short* qb = q + (size_t)bh * 512 * 128;
    const unsigned short* kb = k + (size_t)bh * 512 * 128;
    const unsigned short* vb = vT + (size_t)bh * 128 * 512;  // f16 (d, j)

    __shared__ alignas(16) unsigned short Ks[64][136];   // 17408 B
    __shared__ alignas(16) unsigned short Vs[128][76];   // 19456 B
    __shared__ alignas(16) float cmS[512];               // column mask adds

    const int t = threadIdx.x;
    const int wave = t >> 6, lane = t & 63;
    const int m16 = lane & 15, g4 = lane >> 4;
    const int iw = i0 + wave * 16;

    cmS[t] = (mask[b * 512 + t] == 0.0f) ? -1e9f : 0.0f;
    cmS[256 + t] = (mask[b * 512 + 256 + t] == 0.0f) ? -1e9f : 0.0f;

    // Q fragments: MFMA B-operand (n=i=m16, k=d)
    bf16x8 aq[4];
    #pragma unroll
    for (int c = 0; c < 4; c++)
        aq[c] = *(const bf16x8*)(qb + (size_t)(iw + m16) * 128 + c * 32 + g4 * 8);

    const int krow = t >> 2, kcol = (t & 3) * 32;
    const int vrow = t >> 1, vcol = (t & 1) * 32;

    const float* dbase = dist + ((size_t)b * 512 + iw) * 512;

    // stage chunk 0 + dist chunk-0 prefetch
    float4 dvA[4];
    {
        bf16x8 kp[4], vp[4];
        #pragma unroll
        for (int u = 0; u < 4; u++) {
            kp[u] = *(const bf16x8*)(kb + (size_t)krow * 128 + kcol + u * 8);
            vp[u] = *(const bf16x8*)(vb + (size_t)vrow * 512 + vcol + u * 8);
        }
        #pragma unroll
        for (int jt = 0; jt < 4; jt++)
            dvA[jt] = *(const float4*)&dbase[(size_t)m16 * 512 + jt * 16 + g4 * 4];
        #pragma unroll
        for (int u = 0; u < 4; u++) {
            *(bf16x8*)&Ks[krow][kcol + u * 8] = kp[u];
            union { bf16x8 v8; ushort4 h4[2]; } cv; cv.v8 = vp[u];
            *(ushort4*)&Vs[vrow][vcol + u * 8] = cv.h4[0];
            *(ushort4*)&Vs[vrow][vcol + u * 8 + 4] = cv.h4[1];
        }
    }
    __syncthreads();

    const f32x4 zero = {0.f, 0.f, 0.f, 0.f};
    float rm = -3.0e38f, rl = 0.f;   // per-lane softmax state (row i = iw+m16)
    f32x4 Ot[8] = {zero, zero, zero, zero, zero, zero, zero, zero};

    for (int c = 0; c < 8; c++) {
        const int j0 = c * 64;
        // prefetch next chunk (K, V, dist) into regs
        bf16x8 kp[4], vp[4];
        float4 dvB[4];
        if (c < 7) {
            const int j0n = j0 + 64;
            #pragma unroll
            for (int u = 0; u < 4; u++) {
                kp[u] = *(const bf16x8*)(kb + (size_t)(j0n + krow) * 128 + kcol + u * 8);
                vp[u] = *(const bf16x8*)(vb + (size_t)vrow * 512 + j0n + vcol + u * 8);
            }
            #pragma unroll
            for (int jt = 0; jt < 4; jt++)
                dvB[jt] = *(const float4*)&dbase[(size_t)m16 * 512 + j0n + jt * 16 + g4 * 4];
        }

        // S^T = K*Q^T with C = dist + cm (column mask):
        // lane gets S[i=m16][j = j0 + jt*16 + g4*4 + r]
        f32x4 s[4];
        #pragma unroll
        for (int jt = 0; jt < 4; jt++) {
            float4 cm4 = *(const float4*)&cmS[j0 + jt * 16 + g4 * 4];
            f32x4 a = {dvA[jt].x + cm4.x, dvA[jt].y + cm4.y,
                       dvA[jt].z + cm4.z, dvA[jt].w + cm4.w};
            #pragma unroll
            for (int cc = 0; cc < 4; cc++) {
                bf16x8 kf = *(const bf16x8*)&Ks[jt * 16 + m16][cc * 32 + g4 * 8];
                a = __builtin_amdgcn_mfma_f32_16x16x32_bf16(kf, aq[cc], a, 0, 0, 0);
            }
            s[jt] = a;
        }

        // chunk max: per-lane over 16 + 2 shuffles
        float cm = -3.0e38f;
        #pragma unroll
        for (int jt = 0; jt < 4; jt++)
            #pragma unroll
            for (int r = 0; r < 4; r++) cm = fmaxf(cm, s[jt][r]);
        cm = fmaxf(cm, __shfl_xor(cm, 16));
        cm = fmaxf(cm, __shfl_xor(cm, 32));

        float nm = fmaxf(rm, cm);
        float alpha = __expf(rm - nm);
        rm = nm;
        rl *= alpha;

        // P in f16 regs = PV A-fragments (k = g4*4 + r)
        f16x4 pa[4];
        float ps = 0.f;
        #pragma unroll
        for (int jt = 0; jt < 4; jt++) {
            #pragma unroll
            for (int r = 0; r < 4; r++) {
                float p = __expf(s[jt][r] - rm);
                ps += p;
                pa[jt][r] = (_Float16)p;
            }
        }
        ps += __shfl_xor(ps, 16);
        ps += __shfl_xor(ps, 32);
        rl += ps;

        // rescale Ot (rows g4*4+r) by alpha of those rows
        float a4[4];
        #pragma unroll
        for (int r = 0; r < 4; r++) a4[r] = __shfl(alpha, g4 * 4 + r);
        #pragma unroll
        for (int dt = 0; dt < 8; dt++)
            #pragma unroll
            for (int r = 0; r < 4; r++) Ot[dt][r] *= a4[r];

        // PV: 4 jt x 8 d-tiles, B-frag = conflict-free b64 from Vs
        #pragma unroll
        for (int jt = 0; jt < 4; jt++)
            #pragma unroll
            for (int dt = 0; dt < 8; dt++) {
                f16x4 vf = *(const f16x4*)&Vs[dt * 16 + m16][jt * 16 + g4 * 4];
                Ot[dt] = __builtin_amdgcn_mfma_f32_16x16x16f16(pa[jt], vf, Ot[dt], 0, 0, 0);
            }

        if (c < 7) {
            __syncthreads();
            #pragma unroll
            for (int u = 0; u < 4; u++) {
                *(bf16x8*)&Ks[krow][kcol + u * 8] = kp[u];
                union { bf16x8 v8; ushort4 h4[2]; } cv; cv.v8 = vp[u];
                *(ushort4*)&Vs[vrow][vcol + u * 8] = cv.h4[0];
                *(ushort4*)&Vs[vrow][vcol + u * 8 + 4] = cv.h4[1];
            }
            #pragma unroll
            for (int jt = 0; jt < 4; jt++) dvA[jt] = dvB[jt];
            __syncthreads();
        }
    }

    // epilogue: normalize, stage in freed Ks, coalesced bf16x8 stores
    __syncthreads();
    float rs = (rl > 0.f) ? 1.0f / rl : 0.f;
    float rs4[4];
    #pragma unroll
    for (int r = 0; r < 4; r++) rs4[r] = __shfl(rs, g4 * 4 + r);
    #pragma unroll
    for (int dt = 0; dt < 8; dt++)
        #pragma unroll
        for (int r = 0; r < 4; r++)
            Ks[wave * 16 + g4 * 4 + r][dt * 16 + m16] = f2bf(Ot[dt][r] * rs4[r]);
    #pragma unroll
    for (int u = 0; u < 4; u++) {
        int lin = lane + 64 * u;
        int row = lin >> 4, seg = lin & 15;
        *(bf16x8*)&y[((size_t)(b * 512) + iw + row) * 1024 + h * 128 + seg * 8] =
            *(const bf16x8*)&Ks[wave * 16 + row][seg * 8];
    }
}

// ---------------------------------------------------------------------------
// Kernel 3: output projection via bf16 MFMA with depth-1 register prefetch.
// ---------------------------------------------------------------------------
__global__ __launch_bounds__(256) void oproj_kernel(
    const unsigned short* __restrict__ Y, const unsigned short* __restrict__ woT,
    const float* __restrict__ bo, const float* __restrict__ mask,
    float* __restrict__ out)
{
    const int row0 = blockIdx.x * 32;
    __shared__ alignas(16) unsigned short Ys[32][136];
    __shared__ alignas(16) unsigned short Ws[128][136];
    __shared__ float boS[128];
    __shared__ float mskS[32];

    const int t = threadIdx.x;
    if (t < 128) boS[t] = bo[t];
    if (t < 32) mskS[t] = mask[row0 + t];

    const int wave = t >> 6, lane = t & 63;
    const int m16 = lane & 15, g4 = lane >> 4;
    const int mrow = (wave & 1) * 16, n0 = (wave >> 1) * 64;

    const int yr = t >> 4, yk = (t & 15) * 8;
    const int wn = t >> 4, wk = (t & 15) * 8;

    const f32x4 zero = {0.f, 0.f, 0.f, 0.f};
    f32x4 acc[4] = {zero, zero, zero, zero};

    bf16x8 yp[2], wp[8];
    #pragma unroll
    for (int u = 0; u < 2; u++)
        yp[u] = *(const bf16x8*)&Y[(size_t)(row0 + yr + u * 16) * 1024 + yk];
    #pragma unroll
    for (int u = 0; u < 8; u++)
        wp[u] = *(const bf16x8*)&woT[(size_t)(wn + u * 16) * 1024 + wk];

    for (int c = 0; c < 8; c++) {
        __syncthreads();
        #pragma unroll
        for (int u = 0; u < 2; u++) *(bf16x8*)&Ys[yr + u * 16][yk] = yp[u];
        #pragma unroll
        for (int u = 0; u < 8; u++) *(bf16x8*)&Ws[wn + u * 16][wk] = wp[u];
        __syncthreads();
        if (c < 7) {
            const int kc0 = (c + 1) * 128;
            #pragma unroll
            for (int u = 0; u < 2; u++)
                yp[u] = *(const bf16x8*)&Y[(size_t)(row0 + yr + u * 16) * 1024 + kc0 + yk];
            #pragma unroll
            for (int u = 0; u < 8; u++)
                wp[u] = *(const bf16x8*)&woT[(size_t)(wn + u * 16) * 1024 + kc0 + wk];
        }
        #pragma unroll
        for (int kc = 0; kc < 4; kc++) {
            bf16x8 a = *(const bf16x8*)&Ys[mrow + m16][kc * 32 + g4 * 8];
            #pragma unroll
            for (int nt = 0; nt < 4; nt++) {
                bf16x8 bb = *(const bf16x8*)&Ws[n0 + nt * 16 + m16][kc * 32 + g4 * 8];
                acc[nt] = __builtin_amdgcn_mfma_f32_16x16x32_bf16(a, bb, acc[nt], 0, 0, 0);
            }
        }
    }
    __syncthreads();

    float* Ot = (float*)&Ws[0][0];  // stride 132
    #pragma unroll
    for (int nt = 0; nt < 4; nt++)
        #pragma unroll
        for (int r = 0; r < 4; r++) {
            int rowl = mrow + g4 * 4 + r;
            int col = n0 + nt * 16 + m16;
            Ot[rowl * 132 + col] = (acc[nt][r] + boS[col]) * mskS[rowl];
        }
    __syncthreads();
    #pragma unroll
    for (int u = 0; u < 4; u++) {
        int lin = t + 256 * u; int r = lin >> 5, c4 = lin & 31;
        *(float4*)&out[(size_t)(row0 + r) * 128 + c4 * 4] =
            *(const float4*)&Ot[r * 132 + c4 * 4];
    }
}

extern "C" void kernel_launch(void* const* d_in, const int* in_sizes, int n_in,
                              void* d_out, int out_size, void* d_ws, size_t ws_size,
                              hipStream_t stream) {
    const float* x    = (const float*)d_in[0];
    const float* dist = (const float*)d_in[1];
    const float* mask = (const float*)d_in[2];
    const float* Wq   = (const float*)d_in[3];
    const float* bq   = (const float*)d_in[4];
    const float* Wk   = (const float*)d_in[5];
    const float* bk   = (const float*)d_in[6];
    const float* Wv   = (const float*)d_in[7];
    const float* bv   = (const float*)d_in[8];
    const float* Wo   = (const float*)d_in[9];
    const float* bo   = (const float*)d_in[10];
    float* out = (float*)d_out;

    const size_t per = (size_t)B_ * H_ * N_ * D_;  // 8,388,608 elements
    unsigned short* qb  = (unsigned short*)d_ws;   // bf16 (B,H,N,D)
    unsigned short* kb  = qb + per;                // bf16 (B,H,N,D)
    unsigned short* vb  = kb + per;                // f16  (B,H,D,N)
    unsigned short* yb  = vb + per;                // bf16 (B,N,H*D)
    unsigned short* wTh = yb + per;                // [3][1024][128]
    unsigned short* woT = wTh + 3 * 131072;        // [128][1024]

    prep_kernel<<<512, 256, 0, stream>>>(Wq, Wk, Wv, Wo, wTh, woT);
    qkv_kernel<<<1536, 256, 0, stream>>>(x, mask, wTh, bq, bk, bv, qb, kb, vb);
    attn_kernel<<<1024, 256, 0, stream>>>(qb, kb, vb, dist, mask, yb);
    oproj_kernel<<<256, 256, 0, stream>>>(yb, woT, bo, mask, out);
}